// Round 17
// baseline (210.593 us; speedup 1.0000x reference)
//
#include <hip/hip_runtime.h>
#include <cmath>

#define D_MODEL 512
#define N_HEADS 8
#define HEAD_DIM 64
#define D_FF 2048
#define SEQ 2048
#define BATCH 2
#define MROWS (BATCH * SEQ) /* 4096 */

typedef __attribute__((ext_vector_type(8))) short short8;
typedef __attribute__((ext_vector_type(4))) float float4v;
typedef unsigned short ushort_t;

static __device__ __forceinline__ ushort_t f2bf(float f) {
    union { float f; unsigned u; } v; v.f = f;
    unsigned r = (v.u + 0x7FFFu + ((v.u >> 16) & 1u)) >> 16;
    return (ushort_t)r;
}
static __device__ __forceinline__ ushort_t f2bf_trunc(float f) {
    union { float f; unsigned u; } v; v.f = f;
    return (ushort_t)(v.u >> 16);
}
static __device__ __forceinline__ float bf2f(ushort_t b) {
    union { unsigned u; float f; } v; v.u = ((unsigned)b) << 16;
    return v.f;
}

// async global->LDS, 16B per lane; LDS dest = wave-uniform base (+ lane*16 by HW)
static __device__ __forceinline__ void gload16(const void* g, void* l) {
    __builtin_amdgcn_global_load_lds(
        (__attribute__((address_space(1))) void*)(unsigned long long)g,
        (__attribute__((address_space(3))) void*)(unsigned)(unsigned long long)l,
        16, 0, 0);
}

// ---------------------------------------------------------------------------
// prep: weight transpose/convert (tiles 0..3071) + x fp32->bf16 (3072..5119)
// ---------------------------------------------------------------------------
__global__ __launch_bounds__(256) void prep_k(
    const float* __restrict__ x,
    const float* __restrict__ Wq, const float* __restrict__ Wk,
    const float* __restrict__ Wv, const float* __restrict__ Wo,
    const float* __restrict__ W1, const float* __restrict__ W2,
    ushort_t* __restrict__ xb,
    ushort_t* __restrict__ WqkvT, ushort_t* __restrict__ WoT,
    ushort_t* __restrict__ W1T, ushort_t* __restrict__ W2T)
{
    int tile = blockIdx.x;
    if (tile >= 3072) {                    // x -> bf16
        int i = (tile - 3072) * 256 + threadIdx.x;
        float4 f = ((const float4*)x)[i];
        ushort4 o;
        o.x = f2bf(f.x); o.y = f2bf(f.y); o.z = f2bf(f.z); o.w = f2bf(f.w);
        ((ushort4*)xb)[i] = o;
        return;
    }
    const float* src; ushort_t* dst; int Kd, Nd, tloc;
    if (tile < 1024) {
        int wsel = tile >> 8; tloc = tile & 255; Kd = 512; Nd = 512;
        if (wsel == 0)      { src = Wq; dst = WqkvT; }
        else if (wsel == 1) { src = Wk; dst = WqkvT + (size_t)512 * 512; }
        else if (wsel == 2) { src = Wv; dst = WqkvT + (size_t)1024 * 512; }
        else                { src = Wo; dst = WoT; }
    } else if (tile < 2048) { tloc = tile - 1024; Kd = 512;  Nd = 2048; src = W1; dst = W1T; }
    else                    { tloc = tile - 2048; Kd = 2048; Nd = 512;  src = W2; dst = W2T; }
    int tn = Nd >> 5;
    int k0 = (tloc / tn) << 5, n0 = (tloc % tn) << 5;
    __shared__ float tl[32][33];
    int c = threadIdx.x & 31, r = threadIdx.x >> 5;
    #pragma unroll
    for (int i = 0; i < 4; ++i)
        tl[r + i * 8][c] = src[(size_t)(k0 + r + i * 8) * Nd + n0 + c];
    __syncthreads();
    #pragma unroll
    for (int i = 0; i < 4; ++i)
        dst[(size_t)(n0 + r + i * 8) * Kd + k0 + c] = f2bf(tl[c][r + i * 8]);
}

// ---------------------------------------------------------------------------
// MFMA bf16 GEMM core v2 (round-5 proven): BM=64, BN=128, BK=128, XOR swizzle.
// MODE 1 = bf16 + bias + ReLU output; MODE 2 = fp32 raw split-K partial.
// ---------------------------------------------------------------------------
template <int MODE>
__global__ __launch_bounds__(256) void gemm_std_k(
    const ushort_t* __restrict__ A, const ushort_t* __restrict__ BT,
    const float* __restrict__ bias, void* __restrict__ Cv,
    int N, int K, int Klen, size_t zstride)
{
    __shared__ ushort_t As[64 * 128];    // 16 KB
    __shared__ ushort_t Bs[128 * 128];   // 32 KB

    const int t = threadIdx.x;
    const int w = t >> 6, lane = t & 63, l16 = lane & 15, quad = lane >> 4;
    const int m0 = blockIdx.y * 64;
    const int n0 = blockIdx.x * 128;
    const int kbase = blockIdx.z * Klen;
    const int mbase = (w >> 1) * 32;
    const int nbase = (w & 1) * 64;
    const int lrow = lane >> 4;
    const int lchunk = lane & 15;

    float4v acc[2][4];
    #pragma unroll
    for (int mt = 0; mt < 2; ++mt)
        #pragma unroll
        for (int nt = 0; nt < 4; ++nt)
            acc[mt][nt] = (float4v){0.f, 0.f, 0.f, 0.f};

    for (int ks = kbase; ks < kbase + Klen; ks += 128) {
        __syncthreads();
        for (int c = w; c < 16; c += 4) {
            int rl = c * 4 + lrow;
            gload16(A + (size_t)(m0 + rl) * K + ks + ((lchunk ^ (rl & 7)) << 3),
                    &As[c * 512]);
        }
        for (int c = w; c < 32; c += 4) {
            int rl = c * 4 + lrow;
            gload16(BT + (size_t)(n0 + rl) * K + ks + ((lchunk ^ (rl & 7)) << 3),
                    &Bs[c * 512]);
        }
        __syncthreads();

        #pragma unroll
        for (int co = 0; co < 4; ++co) {
            const int poff = (((co * 4 + quad) ^ (l16 & 7)) << 3);
            short8 af[2], bf8[4];
            #pragma unroll
            for (int mt = 0; mt < 2; ++mt)
                af[mt] = *(const short8*)&As[(mbase + mt * 16 + l16) * 128 + poff];
            #pragma unroll
            for (int nt = 0; nt < 4; ++nt)
                bf8[nt] = *(const short8*)&Bs[(nbase + nt * 16 + l16) * 128 + poff];
            #pragma unroll
            for (int mt = 0; mt < 2; ++mt)
                #pragma unroll
                for (int nt = 0; nt < 4; ++nt)
                    acc[mt][nt] = __builtin_amdgcn_mfma_f32_16x16x32_bf16(
                        af[mt], bf8[nt], acc[mt][nt], 0, 0, 0);
        }
    }

    float* Cf = (float*)Cv + blockIdx.z * zstride;
    #pragma unroll
    for (int mt = 0; mt < 2; ++mt) {
        #pragma unroll
        for (int nt = 0; nt < 4; ++nt) {
            int gcol = n0 + nbase + nt * 16 + l16;
            float b = (MODE == 2) ? 0.f : bias[gcol];
            #pragma unroll
            for (int r = 0; r < 4; ++r) {
                int grow = m0 + mbase + mt * 16 + quad * 4 + r;
                float v = acc[mt][nt][r] + b;
                if (MODE == 1) v = fmaxf(v, 0.f);
                if (MODE == 1) ((ushort_t*)Cv)[(size_t)grow * N + gcol] = f2bf(v);
                else           Cf[(size_t)grow * N + gcol] = v;
            }
        }
    }
}

// ---------------------------------------------------------------------------
// Fused QKV GEMM on the v2 core. Q scale folds 1/sqrt(64) and log2(e).
// ---------------------------------------------------------------------------
__global__ __launch_bounds__(256) void gemm_qkv_k(
    const ushort_t* __restrict__ A, const ushort_t* __restrict__ BT,
    const float* __restrict__ bq, const float* __restrict__ bk,
    const float* __restrict__ bv,
    ushort_t* __restrict__ Qb, ushort_t* __restrict__ Kb,
    ushort_t* __restrict__ VTb)
{
    __shared__ ushort_t As[64 * 128];
    __shared__ ushort_t Bs[128 * 128];

    const int t = threadIdx.x;
    const int w = t >> 6, lane = t & 63, l16 = lane & 15, quad = lane >> 4;
    const int m0 = blockIdx.y * 64;
    const int n0 = blockIdx.x * 128;
    const int mbase = (w >> 1) * 32;
    const int nbase = (w & 1) * 64;
    const int lrow = lane >> 4;
    const int lchunk = lane & 15;
    const int K = 512;

    float4v acc[2][4];
    #pragma unroll
    for (int mt = 0; mt < 2; ++mt)
        #pragma unroll
        for (int nt = 0; nt < 4; ++nt)
            acc[mt][nt] = (float4v){0.f, 0.f, 0.f, 0.f};

    for (int ks = 0; ks < 512; ks += 128) {
        __syncthreads();
        for (int c = w; c < 16; c += 4) {
            int rl = c * 4 + lrow;
            gload16(A + (size_t)(m0 + rl) * K + ks + ((lchunk ^ (rl & 7)) << 3),
                    &As[c * 512]);
        }
        for (int c = w; c < 32; c += 4) {
            int rl = c * 4 + lrow;
            gload16(BT + (size_t)(n0 + rl) * K + ks + ((lchunk ^ (rl & 7)) << 3),
                    &Bs[c * 512]);
        }
        __syncthreads();

        #pragma unroll
        for (int co = 0; co < 4; ++co) {
            const int poff = (((co * 4 + quad) ^ (l16 & 7)) << 3);
            short8 af[2], bf8[4];
            #pragma unroll
            for (int mt = 0; mt < 2; ++mt)
                af[mt] = *(const short8*)&As[(mbase + mt * 16 + l16) * 128 + poff];
            #pragma unroll
            for (int nt = 0; nt < 4; ++nt)
                bf8[nt] = *(const short8*)&Bs[(nbase + nt * 16 + l16) * 128 + poff];
            #pragma unroll
            for (int mt = 0; mt < 2; ++mt)
                #pragma unroll
                for (int nt = 0; nt < 4; ++nt)
                    acc[mt][nt] = __builtin_amdgcn_mfma_f32_16x16x32_bf16(
                        af[mt], bf8[nt], acc[mt][nt], 0, 0, 0);
        }
    }

    const int tsel = n0 >> 9;                       // 0=Q 1=K 2=V (block-uniform)
    const float* bias = (tsel == 0) ? bq : (tsel == 1) ? bk : bv;
    const float scl = (tsel == 0) ? 0.18033688f : 1.0f;  // 0.125 * log2(e)
    ushort_t* dst = (tsel == 0) ? Qb : Kb;

    #pragma unroll
    for (int mt = 0; mt < 2; ++mt) {
        #pragma unroll
        for (int nt = 0; nt < 4; ++nt) {
            int gcol = n0 + nbase + nt * 16 + l16;
            int lcol = gcol - (tsel << 9);
            int h = lcol >> 6, dh = lcol & 63;
            float b = bias[lcol];
            #pragma unroll
            for (int r = 0; r < 4; ++r) {
                int grow = m0 + mbase + mt * 16 + quad * 4 + r;
                int bb = grow >> 11, s = grow & 2047;
                float v = (acc[mt][nt][r] + b) * scl;
                if (tsel < 2)
                    dst[(((size_t)(bb * N_HEADS + h)) * SEQ + s) * HEAD_DIM + dh] = f2bf(v);
                else
                    VTb[(((size_t)(bb * N_HEADS + h)) * HEAD_DIM + dh) * SEQ + s] = f2bf(v);
            }
        }
    }
}

// ---------------------------------------------------------------------------
// bf16 MFMA flash attention v15: 2-WAVE BLOCKS, 32 q-rows/wave (2 m-tiles).
// Each K and V LDS fragment read is shared across both m-tiles -> the
// block's total LDS reads HALVE vs v14 (4 waves each re-reading the tile).
// Regime: v14's minimized-sync structure is LDS-read-bound (~3100 LDS-cyc
// vs ~360 MFMA-cyc per CU-iter modeled) -> this is the lever that round 1
// could not see (old structure was barrier-stall-bound).
// Grid (16,32) x 128 threads; KVBLK=128, ring-2, 16 iters; LDS 64 KB ->
// 2 blocks/CU = 4 waves/CU. rho128 in-register P as v14; per-set rho
// computed with compile-time c (no dynamic indexing). 16 gloads/thread/
// stage -> vmcnt(16). lgkmcnt(0) race fix kept (round-12 evidence).
// ---------------------------------------------------------------------------
__global__ __launch_bounds__(128) void attn_mfma_k(
    const ushort_t* __restrict__ Qg, const ushort_t* __restrict__ Kg,
    const ushort_t* __restrict__ VTg,
    ushort_t* __restrict__ Ctx)
{
    __shared__ __align__(16) ushort_t Kbuf[2][128 * 64];   // 16 KB each
    __shared__ __align__(16) ushort_t Vbuf[2][64 * 128];   // 16 KB each

    const int bh = blockIdx.x;
    const int q0 = blockIdx.y * 64;
    const int t = threadIdx.x;            // 0..127
    const int w = t >> 6;                 // wave 0..1
    const int lane = t & 63;
    const int l16 = lane & 15;
    const int quad = lane >> 4;
    const int qbase = q0 + w * 32;        // wave owns 32 q-rows (2 m-tiles)
    const float NM2 = -14.4269504f;   // -10*log2(e); scores pre-scaled by log2(e)/8

    // K staging: 8 sets; set c covers LDS rows c*16 + rA (rA = t>>3 in 0..15).
    const int rA = t >> 3;                         // 0..15
    const int gk = (t & 7) ^ (rA & 7);             // chunk swizzle (8 chunks/row)
    // V staging: 8 sets; set c covers LDS rows c*8 + rv (rv = t>>4 in 0..7).
    const int rv = t >> 4;                         // 0..7
    const int gv = (t & 15) ^ (rv & 7);            // chunk swizzle (16 chunks/row)
    const size_t kgrow = (size_t)bh * SEQ;         // + key
    const size_t vgrow = (size_t)bh * HEAD_DIM;    // + d

    // rho128(c*16 + rA) = (c>>1)*32 + ((rA&12)<<1) + ((c&1)<<2) + (rA&3)
#define ATTN_STAGE(b, kb)                                                                     \
    {                                                                                         \
        _Pragma("unroll")                                                                     \
        for (int c = 0; c < 8; ++c) {                                                         \
            int kp = (c >> 1) * 32 + ((rA & 12) << 1) + ((c & 1) << 2) + (rA & 3);            \
            gload16(Kg + (kgrow + (kb) + kp) * HEAD_DIM + gk * 8,                             \
                    &Kbuf[b][c * 1024 + w * 512]);                                            \
        }                                                                                     \
        _Pragma("unroll")                                                                     \
        for (int c = 0; c < 8; ++c) {                                                         \
            gload16(VTg + (vgrow + c * 8 + rv) * SEQ + (kb) + gv * 8,                         \
                    &Vbuf[b][c * 1024 + w * 512]);                                            \
        }                                                                                     \
    }

    short8 aq[2][2];
    #pragma unroll
    for (int mt = 0; mt < 2; ++mt) {
        const ushort_t* qp =
            Qg + ((size_t)bh * SEQ + qbase + mt * 16 + l16) * HEAD_DIM + quad * 8;
        aq[mt][0] = *(const short8*)(qp);
        aq[mt][1] = *(const short8*)(qp + 32);
    }

    const short8 ones8 = {(short)0x3F80, (short)0x3F80, (short)0x3F80, (short)0x3F80,
                          (short)0x3F80, (short)0x3F80, (short)0x3F80, (short)0x3F80};

    float4v o[2][4] = {};
    float4v ol[2] = {};   // full softmax denominator via ones-MFMA

    ATTN_STAGE(0, 0)

    for (int i = 0; i < 16; ++i) {
        const int cur = i & 1;
        if (i < 15) {
            ATTN_STAGE(cur ^ 1, (i + 1) * 128)
            asm volatile("s_waitcnt vmcnt(16) lgkmcnt(0)" ::: "memory");  // tile i landed (mine)
        } else {
            asm volatile("s_waitcnt vmcnt(0) lgkmcnt(0)" ::: "memory");
        }
        asm volatile("s_barrier" ::: "memory");               // tile i landed (all)

        const ushort_t* Kc = Kbuf[cur];
        const ushort_t* Vc = Vbuf[cur];

        float4v s[2][8];
        #pragma unroll
        for (int mt = 0; mt < 2; ++mt)
            #pragma unroll
            for (int nt = 0; nt < 8; ++nt)
                s[mt][nt] = (float4v){NM2, NM2, NM2, NM2};   // fold fixed max

        __builtin_amdgcn_s_setprio(1);
        #pragma unroll
        for (int c = 0; c < 2; ++c) {
            const int poff = (((c * 4 + quad) ^ (l16 & 7)) << 3);
            #pragma unroll
            for (int nt = 0; nt < 8; ++nt) {
                short8 bk8 = *(const short8*)&Kc[(nt * 16 + l16) * 64 + poff];
                // swapped: A = K-frag (M=permuted key), B = Q-frag (N=q) -> D = S^T
                #pragma unroll
                for (int mt = 0; mt < 2; ++mt)
                    s[mt][nt] = __builtin_amdgcn_mfma_f32_16x16x32_bf16(
                        bk8, aq[mt][c], s[mt][nt], 0, 0, 0);
            }
        }
        __builtin_amdgcn_s_setprio(0);

        // softmax: p = exp2(score_log2 - M2) (M2 pre-folded into acc init)
        #pragma unroll
        for (int mt = 0; mt < 2; ++mt)
            #pragma unroll
            for (int nt = 0; nt < 8; ++nt)
                #pragma unroll
                for (int r = 0; r < 4; ++r)
                    s[mt][nt][r] = exp2f(s[mt][nt][r]);

        // PV: in-register A per m-tile (af[mt] = standard-order keys
        // 32c+8*quad+{0..7}); V fragment read ONCE, shared by both m-tiles.
        __builtin_amdgcn_s_setprio(1);
        #pragma unroll
        for (int c = 0; c < 4; ++c) {
            short8 af[2];
            #pragma unroll
            for (int mt = 0; mt < 2; ++mt) {
                af[mt][0] = (short)f2bf_trunc(s[mt][2 * c][0]);
                af[mt][1] = (short)f2bf_trunc(s[mt][2 * c][1]);
                af[mt][2] = (short)f2bf_trunc(s[mt][2 * c][2]);
                af[mt][3] = (short)f2bf_trunc(s[mt][2 * c][3]);
                af[mt][4] = (short)f2bf_trunc(s[mt][2 * c + 1][0]);
                af[mt][5] = (short)f2bf_trunc(s[mt][2 * c + 1][1]);
                af[mt][6] = (short)f2bf_trunc(s[mt][2 * c + 1][2]);
                af[mt][7] = (short)f2bf_trunc(s[mt][2 * c + 1][3]);
            }
            const int poff = (((c * 4 + quad) ^ (l16 & 7)) << 3);
            #pragma unroll
            for (int dt = 0; dt < 4; ++dt) {
                short8 bv8 = *(const short8*)&Vc[(dt * 16 + l16) * 128 + poff];
                #pragma unroll
                for (int mt = 0; mt < 2; ++mt)
                    o[mt][dt] = __builtin_amdgcn_mfma_f32_16x16x32_bf16(
                        af[mt], bv8, o[mt][dt], 0, 0, 0);
            }
            #pragma unroll
            for (int mt = 0; mt < 2; ++mt)
                ol[mt] = __builtin_amdgcn_mfma_f32_16x16x32_bf16(
                    af[mt], ones8, ol[mt], 0, 0, 0);
        }
        __builtin_amdgcn_s_setprio(0);

        asm volatile("s_barrier" ::: "memory");   // all waves done with buf[cur]
    }
#undef ATTN_STAGE

    // normalize + direct bf16 Ctx write: ctx[b][q][h*64+d]
    const int bb = bh >> 3, hh = bh & 7;
    #pragma unroll
    for (int mt = 0; mt < 2; ++mt) {
        #pragma unroll
        for (int r = 0; r < 4; ++r) {
            int q = qbase + mt * 16 + quad * 4 + r;
            float inv = 1.0f / ol[mt][r];
            #pragma unroll
            for (int dt = 0; dt < 4; ++dt)
                Ctx[((size_t)(bb * SEQ + q)) * D_MODEL + hh * HEAD_DIM + dt * 16 + l16] =
                    f2bf(o[mt][dt][r] * inv);
        }
    }
}

// ---------------------------------------------------------------------------
// Fused Wo projection + residual + LayerNorm1 (round-8 proven; bf16-only h).
// Block = 16 rows x ALL 512 cols; grid 256 = 1 block/CU.
// ---------------------------------------------------------------------------
__global__ __launch_bounds__(256) void wo_ln_k(
    const ushort_t* __restrict__ Ctx,   // [4096][512] bf16 (A, K contig)
    const ushort_t* __restrict__ WoT,   // [512][512]  bf16 (B rows = out cols)
    const float* __restrict__ x,        // residual fp32
    const float* __restrict__ bo,
    const float* __restrict__ gam, const float* __restrict__ bet,
    ushort_t* __restrict__ Hhb)
{
    __shared__ __align__(16) ushort_t As[16 * 512];      // 16 KB, full K
    __shared__ __align__(16) ushort_t Bs[2][512 * 64];   // 64 KB each
    __shared__ float red[2][4][16];                      // [s|ss][wave][row]

    const int t = threadIdx.x;
    const int w = t >> 6, lane = t & 63, l16 = lane & 15, quad = lane >> 4;
    const int m0 = blockIdx.x * 16;
    const int K = 512;

    #pragma unroll
    for (int p = 0; p < 4; ++p) {
        int row = p * 4 + w;
        int g = (lane & 56) | ((lane & 7) ^ (row & 7));
        gload16(Ctx + (size_t)(m0 + row) * K + g * 8, &As[row * 512]);
    }

#define WOLN_STAGE_B(b, ks)                                                     \
    {                                                                           \
        _Pragma("unroll")                                                       \
        for (int c = 0; c < 16; ++c) {                                          \
            int row = c * 32 + (t >> 3);                                        \
            int g = (t & 7) ^ (row & 7);                                        \
            gload16(WoT + (size_t)row * K + (ks) * 64 + g * 8,                  \
                    &Bs[b][c * 2048 + w * 512]);                                \
        }                                                                       \
    }

    float4v acc[8];
    #pragma unroll
    for (int nt = 0; nt < 8; ++nt) acc[nt] = (float4v){0.f, 0.f, 0.f, 0.f};

    WOLN_STAGE_B(0, 0)

    for (int ks = 0; ks < 8; ++ks) {
        const int cur = ks & 1;
        if (ks < 7) {
            WOLN_STAGE_B(cur ^ 1, ks + 1)
            asm volatile("s_waitcnt vmcnt(16) lgkmcnt(0)" ::: "memory");
        } else {
            asm volatile("s_waitcnt vmcnt(0) lgkmcnt(0)" ::: "memory");
        }
        asm volatile("s_barrier" ::: "memory");

        #pragma unroll
        for (int c = 0; c < 2; ++c) {
            const int poff = (((c * 4 + quad) ^ (l16 & 7)) << 3);
            short8 af = *(const short8*)&As[l16 * 512 + ks * 64 + poff];
            #pragma unroll
            for (int nt = 0; nt < 8; ++nt) {
                short8 bv = *(const short8*)&Bs[cur][(w * 128 + nt * 16 + l16) * 64 + poff];
                acc[nt] = __builtin_amdgcn_mfma_f32_16x16x32_bf16(af, bv, acc[nt], 0, 0, 0);
            }
        }
        asm volatile("s_barrier" ::: "memory");
    }
#undef WOLN_STAGE_B

    float v[8][4];
    float s[4] = {0.f, 0.f, 0.f, 0.f}, ss[4] = {0.f, 0.f, 0.f, 0.f};
    #pragma unroll
    for (int nt = 0; nt < 8; ++nt) {
        int col = w * 128 + nt * 16 + l16;
        float b = bo[col];
        #pragma unroll
        for (int r = 0; r < 4; ++r) {
            int grow = m0 + quad * 4 + r;
            float val = acc[nt][r] + b + x[(size_t)grow * D_MODEL + col];
            v[nt][r] = val;
            s[r] += val;
            ss[r] += val * val;
        }
    }
    #pragma unroll
    for (int r = 0; r < 4; ++r) {
        #pragma unroll
        for (int m = 1; m < 16; m <<= 1) {
            s[r]  += __shfl_xor(s[r], m);
            ss[r] += __shfl_xor(ss[r], m);
        }
    }
    if (l16 == 0) {
        #pragma unroll
        for (int r = 0; r < 4; ++r) {
            red[0][w][quad * 4 + r] = s[r];
            red[1][w][quad * 4 + r] = ss[r];
        }
    }
    __syncthreads();
    #pragma unroll
    for (int r = 0; r < 4; ++r) {
        int lrow = quad * 4 + r;
        float S  = red[0][0][lrow] + red[0][1][lrow] + red[0][2][lrow] + red[0][3][lrow];
        float SS = red[1][0][lrow] + red[1][1][lrow] + red[1][2][lrow] + red[1][3][lrow];
        float mu  = S * (1.0f / D_MODEL);
        float var = SS * (1.0f / D_MODEL) - mu * mu;
        float inv = rsqrtf(var + 1e-5f);
        int grow = m0 + lrow;
        #pragma unroll
        for (int nt = 0; nt < 8; ++nt) {
            int col = w * 128 + nt * 16 + l16;
            float o = (v[nt][r] - mu) * inv * gam[col] + bet[col];
            Hhb[(size_t)grow * D_MODEL + col] = f2bf(o);
        }
    }
}

// ---------------------------------------------------------------------------
// Residual + LayerNorm over split-K partials (LN2, final output).
// Residual X from bf16 Hhb; column-pair layout (thread t owns cols 2t,2t+1).
// ---------------------------------------------------------------------------
__global__ __launch_bounds__(256) void add_ln_k(
    const ushort_t* __restrict__ Xb, const float* __restrict__ P0,
    const float* __restrict__ P1, const float* __restrict__ bias,
    const float* __restrict__ gam, const float* __restrict__ bet,
    float* __restrict__ O)
{
    const int row = blockIdx.x;
    const int t = threadIdx.x;
    const size_t ro = (size_t)row * D_MODEL;
    const int c0 = 2 * t;

    ushort2 xb2 = *(const ushort2*)&Xb[ro + c0];
    float2 p0 = *(const float2*)&P0[ro + c0];
    float2 p1 = *(const float2*)&P1[ro + c0];
    float2 bi = *(const float2*)&bias[c0];
    float v0 = bf2f(xb2.x) + p0.x + p1.x + bi.x;
    float v1 = bf2f(xb2.y) + p0.y + p1.y + bi.y;
    float s = v0 + v1;
    float ss = v0 * v0 + v1 * v1;
    #pragma unroll
    for (int off = 32; off > 0; off >>= 1) {
        s  += __shfl_down(s, off);
        ss += __shfl_down(ss, off);
    }
    __shared__ float sb[4], ssb[4];
    if ((t & 63) == 0) { sb[t >> 6] = s; ssb[t >> 6] = ss; }
    __syncthreads();
    float S  = sb[0] + sb[1] + sb[2] + sb[3];
    float SS = ssb[0] + ssb[1] + ssb[2] + ssb[3];
    float mu  = S * (1.0f / D_MODEL);
    float var = SS * (1.0f / D_MODEL) - mu * mu;
    float inv = rsqrtf(var + 1e-5f);
    float2 gm = *(const float2*)&gam[c0];
    float2 bt2 = *(const float2*)&bet[c0];
    float2 o2;
    o2.x = (v0 - mu) * inv * gm.x + bt2.x;
    o2.y = (v1 - mu) * inv * gm.y + bt2.y;
    *(float2*)&O[ro + c0] = o2;
}

// ---------------------------------------------------------------------------
extern "C" void kernel_launch(void* const* d_in, const int* in_sizes, int n_in,
                              void* d_out, int out_size, void* d_ws, size_t ws_size,
                              hipStream_t stream)
{
    const float* x   = (const float*)d_in[0];
    const float* Wq  = (const float*)d_in[1];
    const float* bq  = (const float*)d_in[2];
    const float* Wk  = (const float*)d_in[3];
    const float* bk  = (const float*)d_in[4];
    const float* Wv  = (const float*)d_in[5];
    const float* bv  = (const float*)d_in[6];
    const float* Wo  = (const float*)d_in[7];
    const float* bo  = (const float*)d_in[8];
    const float* W1  = (const float*)d_in[9];
    const float* b1  = (const float*)d_in[10];
    const float* W2  = (const float*)d_in[11];
    const float* b2  = (const float*)d_in[12];
    const float* g1  = (const float*)d_in[13];
    const float* be1 = (const float*)d_in[14];
    const float* g2  = (const float*)d_in[15];
    const float* be2 = (const float*)d_in[16];
    float* out = (float*)d_out;
    float* ws  = (float*)d_ws;

    // float-unit offsets; workspace is >=268 MB (fillBuffer writes 268 MB).
    ushort_t* WoT   = (ushort_t*)(ws);               // [512][512] bf16
    ushort_t* W1T   = (ushort_t*)(ws + 131072);      // [2048][512]
    ushort_t* W2T   = (ushort_t*)(ws + 655360);      // [512][2048]
    ushort_t* WqkvT = (ushort_t*)(ws + 1179648);     // [1536][512]
    ushort_t* xb    = (ushort_t*)(ws + 1572864);     // [4096][512] bf16
    ushort_t* Qb    = (ushort_t*)(ws + 2621440);     // [16][2048][64]
    ushort_t* Kb    = (ushort_t*)(ws + 3670016);
    ushort_t* VTb   = (ushort_t*)(ws + 4718592);     // [16][64][2048]
    ushort_t* Ctx   = (ushort_t*)(ws + 5767168);     // [4096][512] bf16
    float*    P0    = ws + 8978432;                  // [4096][512] fp32 partial
    float*    P1    = ws + 11075584;                 // [4096][512] fp32 partial
    ushort_t* FF1   = (ushort_t*)(ws + 1572864);     // [4096][2048] bf16 (xb/Qb slot, dead by W1)
    ushort_t* Hhb   = (ushort_t*)(ws + 5767168);     // [4096][512] bf16 (Ctx slot, dead after Wo)

    // conversions (fused)
    prep_k<<<5120, 256, 0, stream>>>(x, Wq, Wk, Wv, Wo, W1, W2, xb, WqkvT, WoT, W1T, W2T);

    // QKV projection: v2 core, 768 blocks = 3/CU exact
    gemm_qkv_k<<<dim3(12, 64), 256, 0, stream>>>(xb, WqkvT, bq, bk, bv, Qb, Kb, VTb);

    // flash attention v15: 2-wave blocks, 32 q/wave, halved LDS reads
    attn_mfma_k<<<dim3(16, 32), 128, 0, stream>>>(Qb, Kb, VTb, Ctx);

    // fused Wo projection + residual + LN1 -> Hhb (bf16 only); 256 blocks
    wo_ln_k<<<256, 256, 0, stream>>>(Ctx, WoT, x, bo, g1, be1, Hhb);

    // FFN up: v2 core, bf16 + bias + ReLU; 1024 blocks
    gemm_std_k<1><<<dim3(16, 64), 256, 0, stream>>>(
        Hhb, W1T, b1, FF1, 2048, 512, 512, 0);

    // FFN down: split-K x2, raw fp32 partials (bias folded into LN2); 512 blocks
    // (round-9 lesson: full-N LN fusion at K=2048 costs 4x B re-read -> keep split-K)
    gemm_std_k<2><<<dim3(4, 64, 2), 256, 0, stream>>>(
        FF1, W2T, nullptr, P0, 512, 2048, 1024, (size_t)MROWS * D_MODEL);

    // out = LN(hb + q0 + q1 + b2)  (residual from bf16 Hhb)
    add_ln_k<<<4096, 256, 0, stream>>>(Hhb, P0, P1, b2, g2, be2, out);
}

// Round 18
// 200.939 us; speedup vs baseline: 1.0480x; 1.0480x over previous
//
#include <hip/hip_runtime.h>
#include <cmath>

#define D_MODEL 512
#define N_HEADS 8
#define HEAD_DIM 64
#define D_FF 2048
#define SEQ 2048
#define BATCH 2
#define MROWS (BATCH * SEQ) /* 4096 */

typedef __attribute__((ext_vector_type(8))) short short8;
typedef __attribute__((ext_vector_type(4))) float float4v;
typedef unsigned short ushort_t;

static __device__ __forceinline__ ushort_t f2bf(float f) {
    union { float f; unsigned u; } v; v.f = f;
    unsigned r = (v.u + 0x7FFFu + ((v.u >> 16) & 1u)) >> 16;
    return (ushort_t)r;
}
static __device__ __forceinline__ ushort_t f2bf_trunc(float f) {
    union { float f; unsigned u; } v; v.f = f;
    return (ushort_t)(v.u >> 16);
}
static __device__ __forceinline__ float bf2f(ushort_t b) {
    union { unsigned u; float f; } v; v.u = ((unsigned)b) << 16;
    return v.f;
}

// async global->LDS, 16B per lane; LDS dest = wave-uniform base (+ lane*16 by HW)
static __device__ __forceinline__ void gload16(const void* g, void* l) {
    __builtin_amdgcn_global_load_lds(
        (__attribute__((address_space(1))) void*)(unsigned long long)g,
        (__attribute__((address_space(3))) void*)(unsigned)(unsigned long long)l,
        16, 0, 0);
}

// ---------------------------------------------------------------------------
// prep: weight transpose/convert (tiles 0..3071) + x fp32->bf16 (3072..5119)
// ---------------------------------------------------------------------------
__global__ __launch_bounds__(256) void prep_k(
    const float* __restrict__ x,
    const float* __restrict__ Wq, const float* __restrict__ Wk,
    const float* __restrict__ Wv, const float* __restrict__ Wo,
    const float* __restrict__ W1, const float* __restrict__ W2,
    ushort_t* __restrict__ xb,
    ushort_t* __restrict__ WqkvT, ushort_t* __restrict__ WoT,
    ushort_t* __restrict__ W1T, ushort_t* __restrict__ W2T)
{
    int tile = blockIdx.x;
    if (tile >= 3072) {                    // x -> bf16
        int i = (tile - 3072) * 256 + threadIdx.x;
        float4 f = ((const float4*)x)[i];
        ushort4 o;
        o.x = f2bf(f.x); o.y = f2bf(f.y); o.z = f2bf(f.z); o.w = f2bf(f.w);
        ((ushort4*)xb)[i] = o;
        return;
    }
    const float* src; ushort_t* dst; int Kd, Nd, tloc;
    if (tile < 1024) {
        int wsel = tile >> 8; tloc = tile & 255; Kd = 512; Nd = 512;
        if (wsel == 0)      { src = Wq; dst = WqkvT; }
        else if (wsel == 1) { src = Wk; dst = WqkvT + (size_t)512 * 512; }
        else if (wsel == 2) { src = Wv; dst = WqkvT + (size_t)1024 * 512; }
        else                { src = Wo; dst = WoT; }
    } else if (tile < 2048) { tloc = tile - 1024; Kd = 512;  Nd = 2048; src = W1; dst = W1T; }
    else                    { tloc = tile - 2048; Kd = 2048; Nd = 512;  src = W2; dst = W2T; }
    int tn = Nd >> 5;
    int k0 = (tloc / tn) << 5, n0 = (tloc % tn) << 5;
    __shared__ float tl[32][33];
    int c = threadIdx.x & 31, r = threadIdx.x >> 5;
    #pragma unroll
    for (int i = 0; i < 4; ++i)
        tl[r + i * 8][c] = src[(size_t)(k0 + r + i * 8) * Nd + n0 + c];
    __syncthreads();
    #pragma unroll
    for (int i = 0; i < 4; ++i)
        dst[(size_t)(n0 + r + i * 8) * Kd + k0 + c] = f2bf(tl[c][r + i * 8]);
}

// ---------------------------------------------------------------------------
// MFMA bf16 GEMM core v2 (round-5 proven): BM=64, BN=128, BK=128, XOR swizzle.
// MODE 1 = bf16 + bias + ReLU output; MODE 2 = fp32 raw split-K partial.
// ---------------------------------------------------------------------------
template <int MODE>
__global__ __launch_bounds__(256) void gemm_std_k(
    const ushort_t* __restrict__ A, const ushort_t* __restrict__ BT,
    const float* __restrict__ bias, void* __restrict__ Cv,
    int N, int K, int Klen, size_t zstride)
{
    __shared__ ushort_t As[64 * 128];    // 16 KB
    __shared__ ushort_t Bs[128 * 128];   // 32 KB

    const int t = threadIdx.x;
    const int w = t >> 6, lane = t & 63, l16 = lane & 15, quad = lane >> 4;
    const int m0 = blockIdx.y * 64;
    const int n0 = blockIdx.x * 128;
    const int kbase = blockIdx.z * Klen;
    const int mbase = (w >> 1) * 32;
    const int nbase = (w & 1) * 64;
    const int lrow = lane >> 4;
    const int lchunk = lane & 15;

    float4v acc[2][4];
    #pragma unroll
    for (int mt = 0; mt < 2; ++mt)
        #pragma unroll
        for (int nt = 0; nt < 4; ++nt)
            acc[mt][nt] = (float4v){0.f, 0.f, 0.f, 0.f};

    for (int ks = kbase; ks < kbase + Klen; ks += 128) {
        __syncthreads();
        for (int c = w; c < 16; c += 4) {
            int rl = c * 4 + lrow;
            gload16(A + (size_t)(m0 + rl) * K + ks + ((lchunk ^ (rl & 7)) << 3),
                    &As[c * 512]);
        }
        for (int c = w; c < 32; c += 4) {
            int rl = c * 4 + lrow;
            gload16(BT + (size_t)(n0 + rl) * K + ks + ((lchunk ^ (rl & 7)) << 3),
                    &Bs[c * 512]);
        }
        __syncthreads();

        #pragma unroll
        for (int co = 0; co < 4; ++co) {
            const int poff = (((co * 4 + quad) ^ (l16 & 7)) << 3);
            short8 af[2], bf8[4];
            #pragma unroll
            for (int mt = 0; mt < 2; ++mt)
                af[mt] = *(const short8*)&As[(mbase + mt * 16 + l16) * 128 + poff];
            #pragma unroll
            for (int nt = 0; nt < 4; ++nt)
                bf8[nt] = *(const short8*)&Bs[(nbase + nt * 16 + l16) * 128 + poff];
            #pragma unroll
            for (int mt = 0; mt < 2; ++mt)
                #pragma unroll
                for (int nt = 0; nt < 4; ++nt)
                    acc[mt][nt] = __builtin_amdgcn_mfma_f32_16x16x32_bf16(
                        af[mt], bf8[nt], acc[mt][nt], 0, 0, 0);
        }
    }

    float* Cf = (float*)Cv + blockIdx.z * zstride;
    #pragma unroll
    for (int mt = 0; mt < 2; ++mt) {
        #pragma unroll
        for (int nt = 0; nt < 4; ++nt) {
            int gcol = n0 + nbase + nt * 16 + l16;
            float b = (MODE == 2) ? 0.f : bias[gcol];
            #pragma unroll
            for (int r = 0; r < 4; ++r) {
                int grow = m0 + mbase + mt * 16 + quad * 4 + r;
                float v = acc[mt][nt][r] + b;
                if (MODE == 1) v = fmaxf(v, 0.f);
                if (MODE == 1) ((ushort_t*)Cv)[(size_t)grow * N + gcol] = f2bf(v);
                else           Cf[(size_t)grow * N + gcol] = v;
            }
        }
    }
}

// ---------------------------------------------------------------------------
// Fused QKV GEMM on the v2 core. Q scale folds 1/sqrt(64) and log2(e).
// ---------------------------------------------------------------------------
__global__ __launch_bounds__(256) void gemm_qkv_k(
    const ushort_t* __restrict__ A, const ushort_t* __restrict__ BT,
    const float* __restrict__ bq, const float* __restrict__ bk,
    const float* __restrict__ bv,
    ushort_t* __restrict__ Qb, ushort_t* __restrict__ Kb,
    ushort_t* __restrict__ VTb)
{
    __shared__ ushort_t As[64 * 128];
    __shared__ ushort_t Bs[128 * 128];

    const int t = threadIdx.x;
    const int w = t >> 6, lane = t & 63, l16 = lane & 15, quad = lane >> 4;
    const int m0 = blockIdx.y * 64;
    const int n0 = blockIdx.x * 128;
    const int mbase = (w >> 1) * 32;
    const int nbase = (w & 1) * 64;
    const int lrow = lane >> 4;
    const int lchunk = lane & 15;
    const int K = 512;

    float4v acc[2][4];
    #pragma unroll
    for (int mt = 0; mt < 2; ++mt)
        #pragma unroll
        for (int nt = 0; nt < 4; ++nt)
            acc[mt][nt] = (float4v){0.f, 0.f, 0.f, 0.f};

    for (int ks = 0; ks < 512; ks += 128) {
        __syncthreads();
        for (int c = w; c < 16; c += 4) {
            int rl = c * 4 + lrow;
            gload16(A + (size_t)(m0 + rl) * K + ks + ((lchunk ^ (rl & 7)) << 3),
                    &As[c * 512]);
        }
        for (int c = w; c < 32; c += 4) {
            int rl = c * 4 + lrow;
            gload16(BT + (size_t)(n0 + rl) * K + ks + ((lchunk ^ (rl & 7)) << 3),
                    &Bs[c * 512]);
        }
        __syncthreads();

        #pragma unroll
        for (int co = 0; co < 4; ++co) {
            const int poff = (((co * 4 + quad) ^ (l16 & 7)) << 3);
            short8 af[2], bf8[4];
            #pragma unroll
            for (int mt = 0; mt < 2; ++mt)
                af[mt] = *(const short8*)&As[(mbase + mt * 16 + l16) * 128 + poff];
            #pragma unroll
            for (int nt = 0; nt < 4; ++nt)
                bf8[nt] = *(const short8*)&Bs[(nbase + nt * 16 + l16) * 128 + poff];
            #pragma unroll
            for (int mt = 0; mt < 2; ++mt)
                #pragma unroll
                for (int nt = 0; nt < 4; ++nt)
                    acc[mt][nt] = __builtin_amdgcn_mfma_f32_16x16x32_bf16(
                        af[mt], bf8[nt], acc[mt][nt], 0, 0, 0);
        }
    }

    const int tsel = n0 >> 9;                       // 0=Q 1=K 2=V (block-uniform)
    const float* bias = (tsel == 0) ? bq : (tsel == 1) ? bk : bv;
    const float scl = (tsel == 0) ? 0.18033688f : 1.0f;  // 0.125 * log2(e)
    ushort_t* dst = (tsel == 0) ? Qb : Kb;

    #pragma unroll
    for (int mt = 0; mt < 2; ++mt) {
        #pragma unroll
        for (int nt = 0; nt < 4; ++nt) {
            int gcol = n0 + nbase + nt * 16 + l16;
            int lcol = gcol - (tsel << 9);
            int h = lcol >> 6, dh = lcol & 63;
            float b = bias[lcol];
            #pragma unroll
            for (int r = 0; r < 4; ++r) {
                int grow = m0 + mbase + mt * 16 + quad * 4 + r;
                int bb = grow >> 11, s = grow & 2047;
                float v = (acc[mt][nt][r] + b) * scl;
                if (tsel < 2)
                    dst[(((size_t)(bb * N_HEADS + h)) * SEQ + s) * HEAD_DIM + dh] = f2bf(v);
                else
                    VTb[(((size_t)(bb * N_HEADS + h)) * HEAD_DIM + dh) * SEQ + s] = f2bf(v);
            }
        }
    }
}

// ---------------------------------------------------------------------------
// bf16 MFMA flash attention v14 (round-16 proven, best): KVBLK=128, ring-2
// double-buffer (2x16KB K + 2x16KB V = 64 KB -> 2 blocks/CU), two-barrier
// pattern, 16 iters. In-register P via K-row permutation
// rho128(p) = (p&0x60)|((p&12)<<1)|((p&16)>>2)|(p&3): swapped QK^T output
// s[nt][r] = score of key 32(nt>>1)+8*quad+4(nt&1)+r, so af[c] =
// {s[2c],s[2c+1]} IS the standard-order PV A-fragment; V read b128
// conflict-free. lgkmcnt(0) in pre-barrier waitcnt is REQUIRED (gfx950
// LDS-DMA write completion is LGKM-tracked; round-12 replay-race evidence).
// ---------------------------------------------------------------------------
__global__ __launch_bounds__(256) void attn_mfma_k(
    const ushort_t* __restrict__ Qg, const ushort_t* __restrict__ Kg,
    const ushort_t* __restrict__ VTg,
    ushort_t* __restrict__ Ctx)
{
    __shared__ __align__(16) ushort_t Kbuf[2][128 * 64];   // 16 KB each
    __shared__ __align__(16) ushort_t Vbuf[2][64 * 128];   // 16 KB each

    const int bh = blockIdx.x;
    const int q0 = blockIdx.y * 64;
    const int t = threadIdx.x;
    const int w = t >> 6;
    const int lane = t & 63;
    const int l16 = lane & 15;
    const int quad = lane >> 4;
    const int qbase = q0 + w * 16;
    const float NM2 = -14.4269504f;   // -10*log2(e); scores pre-scaled by log2(e)/8

    // K staging: 1024 chunks/buffer; set c covers LDS rows c*32 + (t>>3).
    const int rA = t >> 3;                         // 0..31
    const int gk = (t & 7) ^ (rA & 7);             // chunk swizzle (8 chunks/row)
    const int kpA = (rA & 3) | ((rA & 0x0C) << 1) | ((rA & 0x10) >> 2);  // rho128 low bits
    // V staging: rows d = c*16 + (t>>4); 16 chunks/row.
    const int rv = t >> 4;                         // 0..15
    const int gv = (t & 15) ^ (rv & 7);            // chunk swizzle (16 chunks/row)
    const size_t kgrow = (size_t)bh * SEQ;         // + key
    const size_t vgrow = (size_t)bh * HEAD_DIM;    // + d

#define ATTN_STAGE(b, kb)                                                                   \
    {                                                                                       \
        gload16(Kg + (kgrow + (kb) + kpA)      * HEAD_DIM + gk * 8, &Kbuf[b][w * 512]);     \
        gload16(Kg + (kgrow + (kb) + kpA + 32) * HEAD_DIM + gk * 8, &Kbuf[b][2048 + w * 512]); \
        gload16(Kg + (kgrow + (kb) + kpA + 64) * HEAD_DIM + gk * 8, &Kbuf[b][4096 + w * 512]); \
        gload16(Kg + (kgrow + (kb) + kpA + 96) * HEAD_DIM + gk * 8, &Kbuf[b][6144 + w * 512]); \
        gload16(VTg + (vgrow + rv)      * SEQ + (kb) + gv * 8, &Vbuf[b][w * 512]);          \
        gload16(VTg + (vgrow + rv + 16) * SEQ + (kb) + gv * 8, &Vbuf[b][2048 + w * 512]);   \
        gload16(VTg + (vgrow + rv + 32) * SEQ + (kb) + gv * 8, &Vbuf[b][4096 + w * 512]);   \
        gload16(VTg + (vgrow + rv + 48) * SEQ + (kb) + gv * 8, &Vbuf[b][6144 + w * 512]);   \
    }

    short8 aq[2];
    {
        const ushort_t* qp = Qg + ((size_t)bh * SEQ + qbase + l16) * HEAD_DIM + quad * 8;
        aq[0] = *(const short8*)(qp);
        aq[1] = *(const short8*)(qp + 32);
    }

    const short8 ones8 = {(short)0x3F80, (short)0x3F80, (short)0x3F80, (short)0x3F80,
                          (short)0x3F80, (short)0x3F80, (short)0x3F80, (short)0x3F80};

    float4v o[4] = {};
    float4v ol = {};   // full softmax denominator via ones-MFMA

    ATTN_STAGE(0, 0)

    for (int i = 0; i < 16; ++i) {
        const int cur = i & 1;
        if (i < 15) {
            ATTN_STAGE(cur ^ 1, (i + 1) * 128)
            asm volatile("s_waitcnt vmcnt(8) lgkmcnt(0)" ::: "memory");  // tile i landed (mine)
        } else {
            asm volatile("s_waitcnt vmcnt(0) lgkmcnt(0)" ::: "memory");
        }
        asm volatile("s_barrier" ::: "memory");               // tile i landed (all)

        const ushort_t* Kc = Kbuf[cur];
        const ushort_t* Vc = Vbuf[cur];

        float4v s[8];
        #pragma unroll
        for (int nt = 0; nt < 8; ++nt)
            s[nt] = (float4v){NM2, NM2, NM2, NM2};   // fold fixed max

        __builtin_amdgcn_s_setprio(1);
        #pragma unroll
        for (int c = 0; c < 2; ++c) {
            const int poff = (((c * 4 + quad) ^ (l16 & 7)) << 3);
            #pragma unroll
            for (int nt = 0; nt < 8; ++nt) {
                short8 bk8 = *(const short8*)&Kc[(nt * 16 + l16) * 64 + poff];
                // swapped: A = K-frag (M=permuted key), B = Q-frag (N=q) -> D = S^T
                s[nt] = __builtin_amdgcn_mfma_f32_16x16x32_bf16(bk8, aq[c], s[nt], 0, 0, 0);
            }
        }
        __builtin_amdgcn_s_setprio(0);

        // softmax: p = exp2(score_log2 - M2) (M2 pre-folded into acc init)
        #pragma unroll
        for (int nt = 0; nt < 8; ++nt)
            #pragma unroll
            for (int r = 0; r < 4; ++r)
                s[nt][r] = exp2f(s[nt][r]);

        // PV: in-register A (af[c] = standard-order keys 32c+8*quad+{0..7});
        // V read b128 standard order (16 chunks/row, XOR swizzle).
        __builtin_amdgcn_s_setprio(1);
        #pragma unroll
        for (int c = 0; c < 4; ++c) {
            short8 af;
            af[0] = (short)f2bf_trunc(s[2 * c][0]);
            af[1] = (short)f2bf_trunc(s[2 * c][1]);
            af[2] = (short)f2bf_trunc(s[2 * c][2]);
            af[3] = (short)f2bf_trunc(s[2 * c][3]);
            af[4] = (short)f2bf_trunc(s[2 * c + 1][0]);
            af[5] = (short)f2bf_trunc(s[2 * c + 1][1]);
            af[6] = (short)f2bf_trunc(s[2 * c + 1][2]);
            af[7] = (short)f2bf_trunc(s[2 * c + 1][3]);
            const int poff = (((c * 4 + quad) ^ (l16 & 7)) << 3);
            #pragma unroll
            for (int dt = 0; dt < 4; ++dt) {
                short8 bv8 = *(const short8*)&Vc[(dt * 16 + l16) * 128 + poff];
                o[dt] = __builtin_amdgcn_mfma_f32_16x16x32_bf16(af, bv8, o[dt], 0, 0, 0);
            }
            ol = __builtin_amdgcn_mfma_f32_16x16x32_bf16(af, ones8, ol, 0, 0, 0);
        }
        __builtin_amdgcn_s_setprio(0);

        asm volatile("s_barrier" ::: "memory");   // all waves done with buf[cur]
    }
#undef ATTN_STAGE

    // normalize + direct bf16 Ctx write: ctx[b][q][h*64+d]
    const int bb = bh >> 3, hh = bh & 7;
    #pragma unroll
    for (int r = 0; r < 4; ++r) {
        int q = qbase + quad * 4 + r;
        float inv = 1.0f / ol[r];
        #pragma unroll
        for (int dt = 0; dt < 4; ++dt)
            Ctx[((size_t)(bb * SEQ + q)) * D_MODEL + hh * HEAD_DIM + dt * 16 + l16] =
                f2bf(o[dt][r] * inv);
    }
}

// ---------------------------------------------------------------------------
// Fused Wo projection + residual + LayerNorm1 (round-8 proven; bf16-only h).
// Block = 16 rows x ALL 512 cols; grid 256 = 1 block/CU.
// ---------------------------------------------------------------------------
__global__ __launch_bounds__(256) void wo_ln_k(
    const ushort_t* __restrict__ Ctx,   // [4096][512] bf16 (A, K contig)
    const ushort_t* __restrict__ WoT,   // [512][512]  bf16 (B rows = out cols)
    const float* __restrict__ x,        // residual fp32
    const float* __restrict__ bo,
    const float* __restrict__ gam, const float* __restrict__ bet,
    ushort_t* __restrict__ Hhb)
{
    __shared__ __align__(16) ushort_t As[16 * 512];      // 16 KB, full K
    __shared__ __align__(16) ushort_t Bs[2][512 * 64];   // 64 KB each
    __shared__ float red[2][4][16];                      // [s|ss][wave][row]

    const int t = threadIdx.x;
    const int w = t >> 6, lane = t & 63, l16 = lane & 15, quad = lane >> 4;
    const int m0 = blockIdx.x * 16;
    const int K = 512;

    #pragma unroll
    for (int p = 0; p < 4; ++p) {
        int row = p * 4 + w;
        int g = (lane & 56) | ((lane & 7) ^ (row & 7));
        gload16(Ctx + (size_t)(m0 + row) * K + g * 8, &As[row * 512]);
    }

#define WOLN_STAGE_B(b, ks)                                                     \
    {                                                                           \
        _Pragma("unroll")                                                       \
        for (int c = 0; c < 16; ++c) {                                          \
            int row = c * 32 + (t >> 3);                                        \
            int g = (t & 7) ^ (row & 7);                                        \
            gload16(WoT + (size_t)row * K + (ks) * 64 + g * 8,                  \
                    &Bs[b][c * 2048 + w * 512]);                                \
        }                                                                       \
    }

    float4v acc[8];
    #pragma unroll
    for (int nt = 0; nt < 8; ++nt) acc[nt] = (float4v){0.f, 0.f, 0.f, 0.f};

    WOLN_STAGE_B(0, 0)

    for (int ks = 0; ks < 8; ++ks) {
        const int cur = ks & 1;
        if (ks < 7) {
            WOLN_STAGE_B(cur ^ 1, ks + 1)
            asm volatile("s_waitcnt vmcnt(16) lgkmcnt(0)" ::: "memory");
        } else {
            asm volatile("s_waitcnt vmcnt(0) lgkmcnt(0)" ::: "memory");
        }
        asm volatile("s_barrier" ::: "memory");

        #pragma unroll
        for (int c = 0; c < 2; ++c) {
            const int poff = (((c * 4 + quad) ^ (l16 & 7)) << 3);
            short8 af = *(const short8*)&As[l16 * 512 + ks * 64 + poff];
            #pragma unroll
            for (int nt = 0; nt < 8; ++nt) {
                short8 bv = *(const short8*)&Bs[cur][(w * 128 + nt * 16 + l16) * 64 + poff];
                acc[nt] = __builtin_amdgcn_mfma_f32_16x16x32_bf16(af, bv, acc[nt], 0, 0, 0);
            }
        }
        asm volatile("s_barrier" ::: "memory");
    }
#undef WOLN_STAGE_B

    float v[8][4];
    float s[4] = {0.f, 0.f, 0.f, 0.f}, ss[4] = {0.f, 0.f, 0.f, 0.f};
    #pragma unroll
    for (int nt = 0; nt < 8; ++nt) {
        int col = w * 128 + nt * 16 + l16;
        float b = bo[col];
        #pragma unroll
        for (int r = 0; r < 4; ++r) {
            int grow = m0 + quad * 4 + r;
            float val = acc[nt][r] + b + x[(size_t)grow * D_MODEL + col];
            v[nt][r] = val;
            s[r] += val;
            ss[r] += val * val;
        }
    }
    #pragma unroll
    for (int r = 0; r < 4; ++r) {
        #pragma unroll
        for (int m = 1; m < 16; m <<= 1) {
            s[r]  += __shfl_xor(s[r], m);
            ss[r] += __shfl_xor(ss[r], m);
        }
    }
    if (l16 == 0) {
        #pragma unroll
        for (int r = 0; r < 4; ++r) {
            red[0][w][quad * 4 + r] = s[r];
            red[1][w][quad * 4 + r] = ss[r];
        }
    }
    __syncthreads();
    #pragma unroll
    for (int r = 0; r < 4; ++r) {
        int lrow = quad * 4 + r;
        float S  = red[0][0][lrow] + red[0][1][lrow] + red[0][2][lrow] + red[0][3][lrow];
        float SS = red[1][0][lrow] + red[1][1][lrow] + red[1][2][lrow] + red[1][3][lrow];
        float mu  = S * (1.0f / D_MODEL);
        float var = SS * (1.0f / D_MODEL) - mu * mu;
        float inv = rsqrtf(var + 1e-5f);
        int grow = m0 + lrow;
        #pragma unroll
        for (int nt = 0; nt < 8; ++nt) {
            int col = w * 128 + nt * 16 + l16;
            float o = (v[nt][r] - mu) * inv * gam[col] + bet[col];
            Hhb[(size_t)grow * D_MODEL + col] = f2bf(o);
        }
    }
}

// ---------------------------------------------------------------------------
// Residual + LayerNorm over split-K partials (LN2, final output).
// Residual X from bf16 Hhb; column-pair layout (thread t owns cols 2t,2t+1).
// ---------------------------------------------------------------------------
__global__ __launch_bounds__(256) void add_ln_k(
    const ushort_t* __restrict__ Xb, const float* __restrict__ P0,
    const float* __restrict__ P1, const float* __restrict__ bias,
    const float* __restrict__ gam, const float* __restrict__ bet,
    float* __restrict__ O)
{
    const int row = blockIdx.x;
    const int t = threadIdx.x;
    const size_t ro = (size_t)row * D_MODEL;
    const int c0 = 2 * t;

    ushort2 xb2 = *(const ushort2*)&Xb[ro + c0];
    float2 p0 = *(const float2*)&P0[ro + c0];
    float2 p1 = *(const float2*)&P1[ro + c0];
    float2 bi = *(const float2*)&bias[c0];
    float v0 = bf2f(xb2.x) + p0.x + p1.x + bi.x;
    float v1 = bf2f(xb2.y) + p0.y + p1.y + bi.y;
    float s = v0 + v1;
    float ss = v0 * v0 + v1 * v1;
    #pragma unroll
    for (int off = 32; off > 0; off >>= 1) {
        s  += __shfl_down(s, off);
        ss += __shfl_down(ss, off);
    }
    __shared__ float sb[4], ssb[4];
    if ((t & 63) == 0) { sb[t >> 6] = s; ssb[t >> 6] = ss; }
    __syncthreads();
    float S  = sb[0] + sb[1] + sb[2] + sb[3];
    float SS = ssb[0] + ssb[1] + ssb[2] + ssb[3];
    float mu  = S * (1.0f / D_MODEL);
    float var = SS * (1.0f / D_MODEL) - mu * mu;
    float inv = rsqrtf(var + 1e-5f);
    float2 gm = *(const float2*)&gam[c0];
    float2 bt2 = *(const float2*)&bet[c0];
    float2 o2;
    o2.x = (v0 - mu) * inv * gm.x + bt2.x;
    o2.y = (v1 - mu) * inv * gm.y + bt2.y;
    *(float2*)&O[ro + c0] = o2;
}

// ---------------------------------------------------------------------------
extern "C" void kernel_launch(void* const* d_in, const int* in_sizes, int n_in,
                              void* d_out, int out_size, void* d_ws, size_t ws_size,
                              hipStream_t stream)
{
    const float* x   = (const float*)d_in[0];
    const float* Wq  = (const float*)d_in[1];
    const float* bq  = (const float*)d_in[2];
    const float* Wk  = (const float*)d_in[3];
    const float* bk  = (const float*)d_in[4];
    const float* Wv  = (const float*)d_in[5];
    const float* bv  = (const float*)d_in[6];
    const float* Wo  = (const float*)d_in[7];
    const float* bo  = (const float*)d_in[8];
    const float* W1  = (const float*)d_in[9];
    const float* b1  = (const float*)d_in[10];
    const float* W2  = (const float*)d_in[11];
    const float* b2  = (const float*)d_in[12];
    const float* g1  = (const float*)d_in[13];
    const float* be1 = (const float*)d_in[14];
    const float* g2  = (const float*)d_in[15];
    const float* be2 = (const float*)d_in[16];
    float* out = (float*)d_out;
    float* ws  = (float*)d_ws;

    // float-unit offsets; workspace is >=268 MB (fillBuffer writes 268 MB).
    ushort_t* WoT   = (ushort_t*)(ws);               // [512][512] bf16
    ushort_t* W1T   = (ushort_t*)(ws + 131072);      // [2048][512]
    ushort_t* W2T   = (ushort_t*)(ws + 655360);      // [512][2048]
    ushort_t* WqkvT = (ushort_t*)(ws + 1179648);     // [1536][512]
    ushort_t* xb    = (ushort_t*)(ws + 1572864);     // [4096][512] bf16
    ushort_t* Qb    = (ushort_t*)(ws + 2621440);     // [16][2048][64]
    ushort_t* Kb    = (ushort_t*)(ws + 3670016);
    ushort_t* VTb   = (ushort_t*)(ws + 4718592);     // [16][64][2048]
    ushort_t* Ctx   = (ushort_t*)(ws + 5767168);     // [4096][512] bf16
    float*    P0    = ws + 8978432;                  // [4096][512] fp32 partial
    float*    P1    = ws + 11075584;                 // [4096][512] fp32 partial
    ushort_t* FF1   = (ushort_t*)(ws + 1572864);     // [4096][2048] bf16 (xb/Qb slot, dead by W1)
    ushort_t* Hhb   = (ushort_t*)(ws + 5767168);     // [4096][512] bf16 (Ctx slot, dead after Wo)

    // conversions (fused)
    prep_k<<<5120, 256, 0, stream>>>(x, Wq, Wk, Wv, Wo, W1, W2, xb, WqkvT, WoT, W1T, W2T);

    // QKV projection: v2 core, 768 blocks = 3/CU exact
    gemm_qkv_k<<<dim3(12, 64), 256, 0, stream>>>(xb, WqkvT, bq, bk, bv, Qb, Kb, VTb);

    // flash attention v14: KVBLK=128, ring-2, in-register P via rho128
    attn_mfma_k<<<dim3(16, 32), 256, 0, stream>>>(Qb, Kb, VTb, Ctx);

    // fused Wo projection + residual + LN1 -> Hhb (bf16 only); 256 blocks
    wo_ln_k<<<256, 256, 0, stream>>>(Ctx, WoT, x, bo, g1, be1, Hhb);

    // FFN up: v2 core, bf16 + bias + ReLU; 1024 blocks
    gemm_std_k<1><<<dim3(16, 64), 256, 0, stream>>>(
        Hhb, W1T, b1, FF1, 2048, 512, 512, 0);

    // FFN down: split-K x2, raw fp32 partials (bias folded into LN2); 512 blocks
    // (round-9 lesson: full-N LN fusion at K=2048 costs 4x B re-read -> keep split-K)
    gemm_std_k<2><<<dim3(4, 64, 2), 256, 0, stream>>>(
        FF1, W2T, nullptr, P0, 512, 2048, 1024, (size_t)MROWS * D_MODEL);

    // out = LN(hb + q0 + q1 + b2)  (residual from bf16 Hhb)
    add_ln_k<<<4096, 256, 0, stream>>>(Hhb, P0, P1, b2, g2, be2, out);
}